// Round 1
// baseline (490.520 us; speedup 1.0000x reference)
//
#include <hip/hip_runtime.h>

typedef unsigned int u32;
typedef float f32x4 __attribute__((ext_vector_type(4)));
typedef short s16x8 __attribute__((ext_vector_type(8)));

#define LDA 136  // padded LDS row stride (bf16 elems): 272 B = 16*17, keeps b128 16B-aligned, 2-way banks

// workspace layout (bytes)
#define WQT_OFF 0ULL
#define WKT_OFF 32768ULL
#define WVT_OFF 65536ULL
#define OPWT_OFF 98304ULL
#define Q_OFF 114688ULL
#define K_OFF (Q_OFF + 8388608ULL)
#define VT_OFF (K_OFF + 8388608ULL)
#define GATE_OFF (VT_OFF + 8388608ULL)
// total ws need = GATE_OFF + 16777216 = ~40.1 MiB

__device__ __forceinline__ u32 f2bf(float f) {  // RNE float->bf16 bits
  u32 u = __float_as_uint(f);
  return (u + 0x7fffu + ((u >> 16) & 1u)) >> 16;
}

__device__ __forceinline__ void gl_lds16(const void* g, void* l) {
  __builtin_amdgcn_global_load_lds((const __attribute__((address_space(1))) void*)g,
                                   (__attribute__((address_space(3))) void*)l, 16, 0, 0);
}

// ---- k0: transpose weights to bf16; fold a_w * (1/sqrt(128)) * log2(e) into Wk^T ----
__global__ void k0_wt(const float* Wq, const float* Wk, const float* Wv,
                      const float* aw, const float* opW, char* ws) {
  int nt = blockIdx.x;
  int KK = (nt == 3) ? 64 : 128;
  const float* S = (nt == 0) ? Wq : (nt == 1) ? Wk : (nt == 2) ? Wv : opW;
  unsigned short* D = (unsigned short*)(ws + (nt == 0 ? WQT_OFF : nt == 1 ? WKT_OFF : nt == 2 ? WVT_OFF : OPWT_OFF));
  for (int i = threadIdx.x; i < 128 * KK; i += blockDim.x) {
    int d = i / KK, k = i - d * KK;
    float v = S[k * 128 + d];
    if (nt == 1) v *= aw[d] * 0.12751743f;  // (1/sqrt(128)) * log2(e)
    D[i] = (unsigned short)f2bf(v);
  }
}

// ---- k1: Q = h@Wq (bf16 [e][d]), K = h@Wk_scaled ([e][d]), Vt = (h@Wv)^T ([d][e]),
// ----     gate = sigmoid(op_emb@opW + op_b) (fp32 [e][d]) ----
__launch_bounds__(256, 2)
__global__ void k1_proj(const float* __restrict__ h, const float* __restrict__ op_emb,
                        const float* __restrict__ op_b, char* __restrict__ ws) {
  int nt = blockIdx.x, et = blockIdx.y;
  int KK = (nt == 3) ? 64 : 128;
  __shared__ unsigned short bufA[128 * LDA];  // MFMA A operand (rows m, k contiguous)
  __shared__ unsigned short bufB[128 * LDA];  // MFMA B operand (rows n, k contiguous)
  unsigned short* wbuf = (nt == 2) ? bufB : bufA;
  unsigned short* xbuf = (nt == 2) ? bufA : bufB;
  const unsigned short* Wt = (const unsigned short*)(ws + (nt == 0 ? WQT_OFF : nt == 1 ? WKT_OFF : nt == 2 ? WVT_OFF : OPWT_OFF));
  {  // stage W^T (bf16, 128 x KK)
    const u32* Ws = (const u32*)Wt;
    int cnt = 128 * KK / 2;
    for (int i = threadIdx.x; i < cnt; i += 256) {
      int r = (2 * i) / KK, c = 2 * i - r * KK;
      *(u32*)&wbuf[r * LDA + c] = Ws[i];
    }
  }
  {  // stage X fp32 -> bf16 (128 rows x KK)
    const float* X = (nt == 3) ? (op_emb + (size_t)et * 128 * 64) : (h + (size_t)et * 128 * 128);
    int cnt = 128 * KK / 4;
    for (int i = threadIdx.x; i < cnt; i += 256) {
      float4 v = *(const float4*)(X + 4 * i);
      int r = (4 * i) / KK, c = 4 * i - r * KK;
      u32 lo = f2bf(v.x) | (f2bf(v.y) << 16);
      u32 hi = f2bf(v.z) | (f2bf(v.w) << 16);
      *(uint2*)&xbuf[r * LDA + c] = make_uint2(lo, hi);
    }
  }
  __syncthreads();
  int tid = threadIdx.x, w = tid >> 6, lane = tid & 63, l15 = lane & 15, q = lane >> 4;
  int wa = w >> 1, wb = w & 1;
  f32x4 acc[4][4];
#pragma unroll
  for (int a = 0; a < 4; a++)
#pragma unroll
    for (int bq = 0; bq < 4; bq++) acc[a][bq] = f32x4{0.f, 0.f, 0.f, 0.f};
  for (int ks = 0; ks < KK / 32; ks++) {
    s16x8 af[4], bf_[4];
#pragma unroll
    for (int mt = 0; mt < 4; mt++)
      af[mt] = *(const s16x8*)&bufA[(wa * 64 + mt * 16 + l15) * LDA + ks * 32 + q * 8];
#pragma unroll
    for (int n2 = 0; n2 < 4; n2++)
      bf_[n2] = *(const s16x8*)&bufB[(wb * 64 + n2 * 16 + l15) * LDA + ks * 32 + q * 8];
#pragma unroll
    for (int mt = 0; mt < 4; mt++)
#pragma unroll
      for (int n2 = 0; n2 < 4; n2++)
        acc[mt][n2] = __builtin_amdgcn_mfma_f32_16x16x32_bf16(af[mt], bf_[n2], acc[mt][n2], 0, 0, 0);
  }
  // epilogue: C[m][n]; lane holds n = lane&15(+16*n2+64*wb) fixed, m = q*4+reg(+16*mt+64*wa) consecutive
  if (nt <= 1) {  // m=d, n=e -> row-major [e][d], 4 consecutive d per lane
    unsigned short* Dst = (unsigned short*)(ws + (nt == 0 ? Q_OFF : K_OFF));
#pragma unroll
    for (int mt = 0; mt < 4; mt++)
#pragma unroll
      for (int n2 = 0; n2 < 4; n2++) {
        int d0 = wa * 64 + mt * 16 + q * 4;
        int eg = et * 128 + wb * 64 + n2 * 16 + l15;
        f32x4 a = acc[mt][n2];
        u32 lo = f2bf(a[0]) | (f2bf(a[1]) << 16);
        u32 hi = f2bf(a[2]) | (f2bf(a[3]) << 16);
        *(uint2*)(Dst + (size_t)eg * 128 + d0) = make_uint2(lo, hi);
      }
  } else if (nt == 2) {  // m=e, n=d -> Vt[b][d][e], 4 consecutive e per lane
    unsigned short* Dst = (unsigned short*)(ws + VT_OFF);
    int b = et >> 4;
    int ein0 = (et & 15) * 128;
#pragma unroll
    for (int mt = 0; mt < 4; mt++)
#pragma unroll
      for (int n2 = 0; n2 < 4; n2++) {
        int e0b = ein0 + wa * 64 + mt * 16 + q * 4;
        int d = wb * 64 + n2 * 16 + l15;
        f32x4 a = acc[mt][n2];
        u32 lo = f2bf(a[0]) | (f2bf(a[1]) << 16);
        u32 hi = f2bf(a[2]) | (f2bf(a[3]) << 16);
        *(uint2*)(Dst + (size_t)b * 128 * 2048 + (size_t)d * 2048 + e0b) = make_uint2(lo, hi);
      }
  } else {  // gate: m=d, n=e, sigmoid(acc + op_b[d]), fp32 [e][d]
    float* Dst = (float*)(ws + GATE_OFF);
#pragma unroll
    for (int mt = 0; mt < 4; mt++)
#pragma unroll
      for (int n2 = 0; n2 < 4; n2++) {
        int d0 = wa * 64 + mt * 16 + q * 4;
        int eg = et * 128 + wb * 64 + n2 * 16 + l15;
        f32x4 a = acc[mt][n2];
        float4 g4;
        g4.x = 1.f / (1.f + __builtin_amdgcn_exp2f(-(a[0] + op_b[d0 + 0]) * 1.4426950f));
        g4.y = 1.f / (1.f + __builtin_amdgcn_exp2f(-(a[1] + op_b[d0 + 1]) * 1.4426950f));
        g4.z = 1.f / (1.f + __builtin_amdgcn_exp2f(-(a[2] + op_b[d0 + 2]) * 1.4426950f));
        g4.w = 1.f / (1.f + __builtin_amdgcn_exp2f(-(a[3] + op_b[d0 + 3]) * 1.4426950f));
        *(float4*)(Dst + (size_t)eg * 128 + d0) = g4;
      }
  }
}

// ---- k2: fused attention + gate + LayerNorm. One block = 128 query rows of one batch. ----
__launch_bounds__(512, 2)
__global__ void k2_attn(const float* __restrict__ adj, const float* __restrict__ ln_g,
                        const float* __restrict__ ln_b, char* __restrict__ ws,
                        float* __restrict__ out) {
  __shared__ char smem[100864];
  unsigned short* Klds = (unsigned short*)smem;        // 32 KB, XOR-swizzled chunks
  unsigned short* Vlds = (unsigned short*)(smem + 32768);  // 32 KB, XOR-swizzled
  char* PLb = smem + 65536;                            // P [e][l] bf16, stride 272 B
  float* sden = (float*)(smem + 100352);               // 128 fp32 denominators

  const int bid = blockIdx.x;
  const int xcd = bid & 7, slot = bid >> 3;
  const int b = xcd * 2 + (slot >> 4);  // 2 batches per XCD for K/Vt L2 locality
  const int e0 = (slot & 15) << 7;

  const unsigned short* Qg = (const unsigned short*)(ws + Q_OFF) + ((size_t)b * 2048 + e0) * 128;
  const unsigned short* Kg = (const unsigned short*)(ws + K_OFF) + (size_t)b * 2048 * 128;
  const unsigned short* Vtg = (const unsigned short*)(ws + VT_OFF) + (size_t)b * 128 * 2048;
  const float* gateg = (const float*)(ws + GATE_OFF) + ((size_t)b * 2048 + e0) * 128;
  const float* adjg = adj + (size_t)b * 2048 * 2048 + (size_t)e0 * 2048;

  const int tid = threadIdx.x;
  const int w = tid >> 6, lane = tid & 63, l15 = lane & 15, q = lane >> 4;
  const int wh = w >> 2, we = w & 3;  // wave grid: wh = l-half (G1) / d-half (G2), we = e-quarter

  if (tid < 128) sden[tid] = 0.0f;

  // persistent Q B-frags: B[k][n=e] = Q[e][k]
  s16x8 qf[2][4];
#pragma unroll
  for (int et = 0; et < 2; et++) {
    const int e = we * 32 + et * 16 + l15;
#pragma unroll
    for (int ks = 0; ks < 4; ks++)
      qf[et][ks] = *(const s16x8*)(Qg + (size_t)e * 128 + ks * 32 + q * 8);
  }

  f32x4 oacc[4][2];
#pragma unroll
  for (int dt = 0; dt < 4; dt++)
#pragma unroll
    for (int et = 0; et < 2; et++) oacc[dt][et] = f32x4{0.f, 0.f, 0.f, 0.f};
  float dp0 = 0.0f, dp1 = 0.0f;
  float4 adjA[2][4], adjB[2][4];

  // stage K(0), Vt(0) via global_load_lds (XOR chunk swizzle: chunk c of row r -> slot c^(r&15))
#pragma unroll
  for (int j = 0; j < 4; j++) {
    int S = (j * 8 + w) * 64 + lane;
    int r = S >> 4, cp = S & 15, c = cp ^ (r & 15);
    gl_lds16(Kg + (size_t)r * 128 + (c << 3), (char*)Klds + (j * 8 + w) * 1024);
    gl_lds16(Vtg + (size_t)r * 2048 + (c << 3), (char*)Vlds + (j * 8 + w) * 1024);
  }
  // adj(0) straight into C-layout VGPRs
#pragma unroll
  for (int et = 0; et < 2; et++) {
    const int e = we * 32 + et * 16 + l15;
#pragma unroll
    for (int lt = 0; lt < 4; lt++)
      adjA[et][lt] = *(const float4*)(adjg + (size_t)e * 2048 + wh * 64 + lt * 16 + q * 4);
  }

#pragma unroll 2
  for (int it = 0; it < 16; it++) {
    __syncthreads();  // K,Vt tiles ready
    if (it < 15) {    // prefetch adj(it+1): hidden under GEMM1+GEMM2
      const float* ab = adjg + (it + 1) * 128;
#pragma unroll
      for (int et = 0; et < 2; et++) {
        const int e = we * 32 + et * 16 + l15;
#pragma unroll
        for (int lt = 0; lt < 4; lt++)
          adjB[et][lt] = *(const float4*)(ab + (size_t)e * 2048 + wh * 64 + lt * 16 + q * 4);
      }
    }
    // GEMM1: St[l][e] = K_tile @ Q^T  (scale & log2e pre-folded into K)
    f32x4 sacc[4][2];
#pragma unroll
    for (int lt = 0; lt < 4; lt++)
#pragma unroll
      for (int et = 0; et < 2; et++) sacc[lt][et] = f32x4{0.f, 0.f, 0.f, 0.f};
#pragma unroll
    for (int ks = 0; ks < 4; ks++) {
      s16x8 kf[4];
#pragma unroll
      for (int lt = 0; lt < 4; lt++) {
        int l = wh * 64 + lt * 16 + l15;
        kf[lt] = *(const s16x8*)((char*)Klds + l * 256 + (((ks * 4 + q) ^ l15) << 4));
      }
#pragma unroll
      for (int lt = 0; lt < 4; lt++)
#pragma unroll
        for (int et = 0; et < 2; et++)
          sacc[lt][et] = __builtin_amdgcn_mfma_f32_16x16x32_bf16(kf[lt], qf[et][ks], sacc[lt][et], 0, 0, 0);
    }
    // elementwise: P = exp2(max(y,0.2y)*adj); denom accum; pack bf16 -> PL[e][l]
#pragma unroll
    for (int et = 0; et < 2; et++) {
      const int e = we * 32 + et * 16 + l15;
#pragma unroll
      for (int lt = 0; lt < 4; lt++) {
        float4 aj = adjA[et][lt];
        f32x4 s = sacc[lt][et];
        float p0 = __builtin_amdgcn_exp2f(fmaxf(s[0], 0.2f * s[0]) * aj.x);
        float p1 = __builtin_amdgcn_exp2f(fmaxf(s[1], 0.2f * s[1]) * aj.y);
        float p2 = __builtin_amdgcn_exp2f(fmaxf(s[2], 0.2f * s[2]) * aj.z);
        float p3 = __builtin_amdgcn_exp2f(fmaxf(s[3], 0.2f * s[3]) * aj.w);
        float sum4 = (p0 + p1) + (p2 + p3);
        if (et == 0) dp0 += sum4; else dp1 += sum4;
        u32 lo = f2bf(p0) | (f2bf(p1) << 16);
        u32 hi = f2bf(p2) | (f2bf(p3) << 16);
        *(uint2*)(PLb + (size_t)e * 272 + ((wh * 64 + lt * 16 + q * 4) << 1)) = make_uint2(lo, hi);
      }
    }
    __syncthreads();  // PL visible; Klds free
    if (it < 15) {    // stage K(it+1) overlapped with GEMM2
      const unsigned short* kb = Kg + (size_t)(it + 1) * 128 * 128;
#pragma unroll
      for (int j = 0; j < 4; j++) {
        int S = (j * 8 + w) * 64 + lane;
        int r = S >> 4, cp = S & 15, c = cp ^ (r & 15);
        gl_lds16(kb + (size_t)r * 128 + (c << 3), (char*)Klds + (j * 8 + w) * 1024);
      }
    }
    // GEMM2: O[d][e] += Vt_tile @ P^T
#pragma unroll
    for (int ks = 0; ks < 4; ks++) {
      s16x8 vf[4], pf[2];
#pragma unroll
      for (int dt = 0; dt < 4; dt++) {
        int d = wh * 64 + dt * 16 + l15;
        vf[dt] = *(const s16x8*)((char*)Vlds + d * 256 + (((ks * 4 + q) ^ l15) << 4));
      }
#pragma unroll
      for (int et = 0; et < 2; et++) {
        const int e = we * 32 + et * 16 + l15;
        pf[et] = *(const s16x8*)(PLb + (size_t)e * 272 + ks * 64 + q * 16);
      }
#pragma unroll
      for (int dt = 0; dt < 4; dt++)
#pragma unroll
        for (int et = 0; et < 2; et++)
          oacc[dt][et] = __builtin_amdgcn_mfma_f32_16x16x32_bf16(vf[dt], pf[et], oacc[dt][et], 0, 0, 0);
    }
    __syncthreads();  // Vlds/PL free
    if (it < 15) {    // stage Vt(it+1); mostly L2 hits due to XCD swizzle
      const unsigned short* vb = Vtg + (size_t)(it + 1) * 128;
#pragma unroll
      for (int j = 0; j < 4; j++) {
        int S = (j * 8 + w) * 64 + lane;
        int r = S >> 4, cp = S & 15, c = cp ^ (r & 15);
        gl_lds16(vb + (size_t)r * 2048 + (c << 3), (char*)Vlds + (j * 8 + w) * 1024);
      }
#pragma unroll
      for (int et = 0; et < 2; et++)
#pragma unroll
        for (int lt = 0; lt < 4; lt++) adjA[et][lt] = adjB[et][lt];
    }
  }

  // denominator reduce (8 lanes contribute per e)
  atomicAdd(&sden[we * 32 + l15], dp0);
  atomicAdd(&sden[we * 32 + 16 + l15], dp1);
  __syncthreads();
  const float inv0 = 1.0f / sden[we * 32 + l15];
  const float inv1 = 1.0f / sden[we * 32 + 16 + l15];
  // O2[e][d] fp32, stride 132 (overlays dead K/V/PL buffers)
  float* O2 = (float*)smem;
#pragma unroll
  for (int dt = 0; dt < 4; dt++)
#pragma unroll
    for (int et = 0; et < 2; et++) {
      const int e = we * 32 + et * 16 + l15;
      const int d0 = wh * 64 + dt * 16 + q * 4;
      f32x4 v = oacc[dt][et];
      const float inv = et ? inv1 : inv0;
      float4 o;
      o.x = v[0] * inv; o.y = v[1] * inv; o.z = v[2] * inv; o.w = v[3] * inv;
      *(float4*)(O2 + e * 132 + d0) = o;
    }
  __syncthreads();
  // LayerNorm: 4 threads per token, 32 features each
  {
    const int e = tid >> 2, j = tid & 3;
    const float* row = O2 + e * 132 + j * 32;
    const float* gr = gateg + (size_t)e * 128 + j * 32;
    float4 x[8];
    float s1 = 0.f, s2 = 0.f;
#pragma unroll
    for (int i = 0; i < 8; i++) {
      float4 v = *(const float4*)(row + i * 4);
      float4 g = *(const float4*)(gr + i * 4);
      float4 hp;
      hp.x = v.x * g.x; hp.y = v.y * g.y; hp.z = v.z * g.z; hp.w = v.w * g.w;
      x[i] = hp;
      s1 += (hp.x + hp.y) + (hp.z + hp.w);
      s2 += (hp.x * hp.x + hp.y * hp.y) + (hp.z * hp.z + hp.w * hp.w);
    }
    s1 += __shfl_xor(s1, 1); s2 += __shfl_xor(s2, 1);
    s1 += __shfl_xor(s1, 2); s2 += __shfl_xor(s2, 2);
    const float mu = s1 * 0.0078125f;
    const float var = s2 * 0.0078125f - mu * mu;
    const float rs = rsqrtf(var + 1e-5f);
    float* orow = out + ((size_t)b * 2048 + e0 + e) * 128 + j * 32;
    const float* gg = ln_g + j * 32;
    const float* bb = ln_b + j * 32;
#pragma unroll
    for (int i = 0; i < 8; i++) {
      float4 gv = *(const float4*)(gg + i * 4);
      float4 bv = *(const float4*)(bb + i * 4);
      float4 o;
      o.x = (x[i].x - mu) * rs * gv.x + bv.x;
      o.y = (x[i].y - mu) * rs * gv.y + bv.y;
      o.z = (x[i].z - mu) * rs * gv.z + bv.z;
      o.w = (x[i].w - mu) * rs * gv.w + bv.w;
      *(float4*)(orow + i * 4) = o;
    }
  }
}

extern "C" void kernel_launch(void* const* d_in, const int* in_sizes, int n_in,
                              void* d_out, int out_size, void* d_ws, size_t ws_size,
                              hipStream_t stream) {
  const float* h = (const float*)d_in[0];
  const float* adj = (const float*)d_in[1];
  const float* op_emb = (const float*)d_in[2];
  const float* Wk = (const float*)d_in[3];
  const float* Wq = (const float*)d_in[4];
  const float* Wv = (const float*)d_in[5];
  const float* a_w = (const float*)d_in[6];
  const float* op_W = (const float*)d_in[7];
  const float* op_b = (const float*)d_in[8];
  const float* ln_g = (const float*)d_in[9];
  const float* ln_b = (const float*)d_in[10];
  char* ws = (char*)d_ws;
  float* out = (float*)d_out;

  k0_wt<<<4, 256, 0, stream>>>(Wq, Wk, Wv, a_w, op_W, ws);
  k1_proj<<<dim3(4, 256), 256, 0, stream>>>(h, op_emb, op_b, ws);
  k2_attn<<<256, 512, 0, stream>>>(adj, ln_g, ln_b, ws, out);
}

// Round 3
// 483.008 us; speedup vs baseline: 1.0156x; 1.0156x over previous
//
#include <hip/hip_runtime.h>

typedef unsigned int u32;
typedef float f32x4 __attribute__((ext_vector_type(4)));
typedef short s16x8 __attribute__((ext_vector_type(8)));

#define LDA 136  // padded LDS row stride (bf16 elems): 272 B, 16B-aligned b128 reads, 2-way banks

// workspace layout (bytes)
#define WQT_OFF 0ULL
#define WKT_OFF 32768ULL
#define WVT_OFF 65536ULL
#define OPWT_OFF 98304ULL
#define Q_OFF 114688ULL
#define K_OFF (Q_OFF + 8388608ULL)
#define VT_OFF (K_OFF + 8388608ULL)
#define GATE_OFF (VT_OFF + 8388608ULL)
#define BITS_OFF (GATE_OFF + 16777216ULL)
// total ws need = BITS_OFF + 8 MiB ~= 48.5 MiB (ws_size ~1 GiB per harness fill trace)

__device__ __forceinline__ u32 f2bf(float f) {  // RNE float->bf16 bits
  u32 u = __float_as_uint(f);
  return (u + 0x7fffu + ((u >> 16) & 1u)) >> 16;
}

__device__ __forceinline__ void gl_lds16(const void* g, void* l) {
  __builtin_amdgcn_global_load_lds((const __attribute__((address_space(1))) void*)g,
                                   (__attribute__((address_space(3))) void*)l, 16, 0, 0);
}

// ---- k_adjbits: compress adj (fp32 {0,1}, 268 MB) to 1-bit masks (8.4 MB),
// ---- pre-permuted into k2's (block, iter, thread) consumption order. Pure streaming.
__global__ void k_adjbits(const float* __restrict__ adj, char* __restrict__ ws) {
  const int bid = blockIdx.x;
  const int lt_ = bid & 15, et_ = (bid >> 4) & 15, b = bid >> 8;
  const float* ag = adj + ((size_t)b * 2048 + et_ * 128) * 2048 + lt_ * 128;
  __shared__ unsigned char flg[128 * 132];  // nonzero flags, stride 132 breaks pack-phase bank conflict
  const int tid = threadIdx.x;
#pragma unroll
  for (int k = 0; k < 8; k++) {  // 8*512 = 4096 float4 = 128x128 tile exactly
    int idx = k * 512 + tid;
    int r = idx >> 5, c = (idx & 31) * 4;
    float4 v = *(const float4*)(ag + (size_t)r * 2048 + c);
    u32 f = (u32)(v.x != 0.0f) | ((u32)(v.y != 0.0f) << 8) | ((u32)(v.z != 0.0f) << 16) |
            ((u32)(v.w != 0.0f) << 24);
    *(u32*)&flg[r * 132 + c] = f;
  }
  __syncthreads();
  const int w = tid >> 6, lane = tid & 63, l15 = lane & 15, q = lane >> 4;
  const int wh = w >> 2, we = w & 3;
  u32 word = 0;
#pragma unroll
  for (int et = 0; et < 2; et++)
#pragma unroll
    for (int lt = 0; lt < 4; lt++) {
      int e = we * 32 + et * 16 + l15;
      int l0 = wh * 64 + lt * 16 + q * 4;
      u32 fw = *(const u32*)&flg[e * 132 + l0];
      u32 nib = ((fw * 0x01020408u) >> 24) & 0xFu;  // b0|b1<<1|b2<<2|b3<<3 (carry-free)
      word |= nib << ((et * 4 + lt) * 4);           // 8 nibbles, shifts 0..28
    }
  u32* bits = (u32*)(ws + BITS_OFF);
  bits[(size_t)((b * 16 + et_) * 16 + lt_) * 512 + tid] = word;
}

// ---- k0: transpose weights to bf16; fold a_w * (1/sqrt(128)) * log2(e) into Wk^T ----
__global__ void k0_wt(const float* Wq, const float* Wk, const float* Wv,
                      const float* aw, const float* opW, char* ws) {
  int nt = blockIdx.x, part = blockIdx.y;
  int kksh = (nt == 3) ? 6 : 7;
  int KK = 1 << kksh;
  const float* S = (nt == 0) ? Wq : (nt == 1) ? Wk : (nt == 2) ? Wv : opW;
  unsigned short* D = (unsigned short*)(ws + (nt == 0 ? WQT_OFF : nt == 1 ? WKT_OFF : nt == 2 ? WVT_OFF : OPWT_OFF));
  int base = part * 8 * KK;
  for (int i = threadIdx.x; i < 8 * KK; i += 256) {
    int d = part * 8 + (i >> kksh), k = i & (KK - 1);
    float v = S[k * 128 + d];
    if (nt == 1) v *= aw[d] * 0.12751743f;  // (1/sqrt(128)) * log2(e)
    D[base + i] = (unsigned short)f2bf(v);
  }
}

// ---- k1: Q = h@Wq (bf16 [e][d]), K = h@Wk_scaled ([e][d]), Vt = (h@Wv)^T ([d][e]),
// ----     gate = sigmoid(op_emb@opW + op_b) (fp32 [e][d]) ----
__launch_bounds__(256, 2)
__global__ void k1_proj(const float* __restrict__ h, const float* __restrict__ op_emb,
                        const float* __restrict__ op_b, char* __restrict__ ws) {
  int nt = blockIdx.x, et = blockIdx.y;
  int kksh = (nt == 3) ? 6 : 7;
  int KK = 1 << kksh;
  __shared__ unsigned short bufA[128 * LDA];  // MFMA A operand (rows m, k contiguous)
  __shared__ unsigned short bufB[128 * LDA];  // MFMA B operand (rows n, k contiguous)
  unsigned short* wbuf = (nt == 2) ? bufB : bufA;
  unsigned short* xbuf = (nt == 2) ? bufA : bufB;
  const unsigned short* Wt = (const unsigned short*)(ws + (nt == 0 ? WQT_OFF : nt == 1 ? WKT_OFF : nt == 2 ? WVT_OFF : OPWT_OFF));
  {  // stage W^T (bf16, 128 x KK) with uint4
    const uint4* Ws = (const uint4*)Wt;
    int cnt = 128 * KK / 8;
    for (int i = threadIdx.x; i < cnt; i += 256) {
      uint4 v = Ws[i];
      int r = (8 * i) >> kksh, c = (8 * i) & (KK - 1);
      *(uint4*)&wbuf[r * LDA + c] = v;
    }
  }
  {  // stage X fp32 -> bf16 (128 rows x KK)
    const float* X = (nt == 3) ? (op_emb + (size_t)et * 128 * 64) : (h + (size_t)et * 128 * 128);
    int cnt = 128 * KK / 4;
    for (int i = threadIdx.x; i < cnt; i += 256) {
      float4 v = *(const float4*)(X + 4 * i);
      int r = (4 * i) >> kksh, c = (4 * i) & (KK - 1);
      u32 lo = f2bf(v.x) | (f2bf(v.y) << 16);
      u32 hi = f2bf(v.z) | (f2bf(v.w) << 16);
      *(uint2*)&xbuf[r * LDA + c] = make_uint2(lo, hi);
    }
  }
  __syncthreads();
  int tid = threadIdx.x, w = tid >> 6, lane = tid & 63, l15 = lane & 15, q = lane >> 4;
  int wa = w >> 1, wb = w & 1;
  f32x4 acc[4][4];
#pragma unroll
  for (int a = 0; a < 4; a++)
#pragma unroll
    for (int bq = 0; bq < 4; bq++) acc[a][bq] = f32x4{0.f, 0.f, 0.f, 0.f};
  for (int ks = 0; ks < KK / 32; ks++) {
    s16x8 af[4], bf_[4];
#pragma unroll
    for (int mt = 0; mt < 4; mt++)
      af[mt] = *(const s16x8*)&bufA[(wa * 64 + mt * 16 + l15) * LDA + ks * 32 + q * 8];
#pragma unroll
    for (int n2 = 0; n2 < 4; n2++)
      bf_[n2] = *(const s16x8*)&bufB[(wb * 64 + n2 * 16 + l15) * LDA + ks * 32 + q * 8];
#pragma unroll
    for (int mt = 0; mt < 4; mt++)
#pragma unroll
      for (int n2 = 0; n2 < 4; n2++)
        acc[mt][n2] = __builtin_amdgcn_mfma_f32_16x16x32_bf16(af[mt], bf_[n2], acc[mt][n2], 0, 0, 0);
  }
  // epilogue: C[m][n]; lane holds n fixed, m = q*4+reg consecutive
  if (nt <= 1) {  // m=d, n=e -> row-major [e][d], 4 consecutive d per lane
    unsigned short* Dst = (unsigned short*)(ws + (nt == 0 ? Q_OFF : K_OFF));
#pragma unroll
    for (int mt = 0; mt < 4; mt++)
#pragma unroll
      for (int n2 = 0; n2 < 4; n2++) {
        int d0 = wa * 64 + mt * 16 + q * 4;
        int eg = et * 128 + wb * 64 + n2 * 16 + l15;
        f32x4 a = acc[mt][n2];
        u32 lo = f2bf(a[0]) | (f2bf(a[1]) << 16);
        u32 hi = f2bf(a[2]) | (f2bf(a[3]) << 16);
        *(uint2*)(Dst + (size_t)eg * 128 + d0) = make_uint2(lo, hi);
      }
  } else if (nt == 2) {  // m=e, n=d -> Vt[b][d][e], 4 consecutive e per lane
    unsigned short* Dst = (unsigned short*)(ws + VT_OFF);
    int b = et >> 4;
    int ein0 = (et & 15) * 128;
#pragma unroll
    for (int mt = 0; mt < 4; mt++)
#pragma unroll
      for (int n2 = 0; n2 < 4; n2++) {
        int e0b = ein0 + wa * 64 + mt * 16 + q * 4;
        int d = wb * 64 + n2 * 16 + l15;
        f32x4 a = acc[mt][n2];
        u32 lo = f2bf(a[0]) | (f2bf(a[1]) << 16);
        u32 hi = f2bf(a[2]) | (f2bf(a[3]) << 16);
        *(uint2*)(Dst + (size_t)b * 128 * 2048 + (size_t)d * 2048 + e0b) = make_uint2(lo, hi);
      }
  } else {  // gate: m=d, n=e, sigmoid(acc + op_b[d]), fp32 [e][d]
    float* Dst = (float*)(ws + GATE_OFF);
#pragma unroll
    for (int mt = 0; mt < 4; mt++)
#pragma unroll
      for (int n2 = 0; n2 < 4; n2++) {
        int d0 = wa * 64 + mt * 16 + q * 4;
        int eg = et * 128 + wb * 64 + n2 * 16 + l15;
        f32x4 a = acc[mt][n2];
        float4 g4;
        g4.x = 1.f / (1.f + __builtin_amdgcn_exp2f(-(a[0] + op_b[d0 + 0]) * 1.4426950f));
        g4.y = 1.f / (1.f + __builtin_amdgcn_exp2f(-(a[1] + op_b[d0 + 1]) * 1.4426950f));
        g4.z = 1.f / (1.f + __builtin_amdgcn_exp2f(-(a[2] + op_b[d0 + 2]) * 1.4426950f));
        g4.w = 1.f / (1.f + __builtin_amdgcn_exp2f(-(a[3] + op_b[d0 + 3]) * 1.4426950f));
        *(float4*)(Dst + (size_t)eg * 128 + d0) = g4;
      }
  }
}

// ---- k2: fused attention + gate + LayerNorm. One block = 128 query rows of one batch. ----
__launch_bounds__(512, 2)
__global__ void k2_attn(const float* __restrict__ ln_g, const float* __restrict__ ln_b,
                        char* __restrict__ ws, float* __restrict__ out) {
  __shared__ char smem[100864];
  unsigned short* Klds = (unsigned short*)smem;            // 32 KB, XOR-swizzled chunks
  unsigned short* Vlds = (unsigned short*)(smem + 32768);  // 32 KB, XOR-swizzled
  char* PLb = smem + 65536;                                // P [e][l] bf16, stride 272 B
  float* sden = (float*)(smem + 100352);                   // 128 fp32 denominators

  const int bid = blockIdx.x;
  const int xcd = bid & 7, slot = bid >> 3;
  const int b = xcd * 2 + (slot >> 4);  // 2 batches per XCD for K/Vt L2 locality
  const int etile = slot & 15;
  const int e0 = etile << 7;

  const unsigned short* Qg = (const unsigned short*)(ws + Q_OFF) + ((size_t)b * 2048 + e0) * 128;
  const unsigned short* Kg = (const unsigned short*)(ws + K_OFF) + (size_t)b * 2048 * 128;
  const unsigned short* Vtg = (const unsigned short*)(ws + VT_OFF) + (size_t)b * 128 * 2048;
  const float* gateg = (const float*)(ws + GATE_OFF) + ((size_t)b * 2048 + e0) * 128;

  const int tid = threadIdx.x;
  const int w = tid >> 6, lane = tid & 63, l15 = lane & 15, q = lane >> 4;
  const int wh = w >> 2, we = w & 3;  // wave grid: wh = l-half (G1) / d-half (G2), we = e-quarter

  const u32* bitg = (const u32*)(ws + BITS_OFF) + (size_t)((b * 16 + etile) * 16) * 512 + tid;

  if (tid < 128) sden[tid] = 0.0f;

  // persistent Q B-frags: B[k][n=e] = Q[e][k]
  s16x8 qf[2][4];
#pragma unroll
  for (int et = 0; et < 2; et++) {
    const int e = we * 32 + et * 16 + l15;
#pragma unroll
    for (int ks = 0; ks < 4; ks++)
      qf[et][ks] = *(const s16x8*)(Qg + (size_t)e * 128 + ks * 32 + q * 8);
  }

  f32x4 oacc[4][2];
#pragma unroll
  for (int dt = 0; dt < 4; dt++)
#pragma unroll
    for (int et = 0; et < 2; et++) oacc[dt][et] = f32x4{0.f, 0.f, 0.f, 0.f};
  float dp0 = 0.0f, dp1 = 0.0f;

  // stage K(0), Vt(0) via global_load_lds (XOR chunk swizzle: chunk c of row r -> slot c^(r&15))
#pragma unroll
  for (int j = 0; j < 4; j++) {
    int S = (j * 8 + w) * 64 + lane;
    int r = S >> 4, cp = S & 15, c = cp ^ (r & 15);
    gl_lds16(Kg + (size_t)r * 128 + (c << 3), (char*)Klds + (j * 8 + w) * 1024);
    gl_lds16(Vtg + (size_t)r * 2048 + (c << 3), (char*)Vlds + (j * 8 + w) * 1024);
  }
  u32 bitA = bitg[0], bitB = 0;  // adj mask for iter 0 (32 bits = this thread's 32 adj cells)

#pragma unroll 2
  for (int it = 0; it < 16; it++) {
    __syncthreads();  // K,Vt tiles ready
    if (it < 15) bitB = bitg[(it + 1) * 512];  // prefetch next iter's adj bits (4 B)
    // GEMM1: St[l][e] = K_tile @ Q^T  (scale & log2e pre-folded into K)
    f32x4 sacc[4][2];
#pragma unroll
    for (int lt = 0; lt < 4; lt++)
#pragma unroll
      for (int et = 0; et < 2; et++) sacc[lt][et] = f32x4{0.f, 0.f, 0.f, 0.f};
#pragma unroll
    for (int ks = 0; ks < 4; ks++) {
      s16x8 kf[4];
#pragma unroll
      for (int lt = 0; lt < 4; lt++) {
        int l = wh * 64 + lt * 16 + l15;
        kf[lt] = *(const s16x8*)((char*)Klds + l * 256 + (((ks * 4 + q) ^ l15) << 4));
      }
#pragma unroll
      for (int lt = 0; lt < 4; lt++)
#pragma unroll
        for (int et = 0; et < 2; et++)
          sacc[lt][et] = __builtin_amdgcn_mfma_f32_16x16x32_bf16(kf[lt], qf[et][ks], sacc[lt][et], 0, 0, 0);
    }
    // elementwise: P = bit ? exp2(lrelu(s)) : exp2(0)=1; denom accum; pack bf16 -> PL[e][l]
#pragma unroll
    for (int et = 0; et < 2; et++) {
      const int e = we * 32 + et * 16 + l15;
#pragma unroll
      for (int lt = 0; lt < 4; lt++) {
        u32 nib = bitA >> ((et * 4 + lt) * 4);  // matches k_adjbits pack, shifts 0..28
        f32x4 s = sacc[lt][et];
        float e0_ = __builtin_amdgcn_exp2f(fmaxf(s[0], 0.2f * s[0]));
        float e1_ = __builtin_amdgcn_exp2f(fmaxf(s[1], 0.2f * s[1]));
        float e2_ = __builtin_amdgcn_exp2f(fmaxf(s[2], 0.2f * s[2]));
        float e3_ = __builtin_amdgcn_exp2f(fmaxf(s[3], 0.2f * s[3]));
        float p0 = (nib & 1u) ? e0_ : 1.0f;
        float p1 = (nib & 2u) ? e1_ : 1.0f;
        float p2 = (nib & 4u) ? e2_ : 1.0f;
        float p3 = (nib & 8u) ? e3_ : 1.0f;
        float sum4 = (p0 + p1) + (p2 + p3);
        if (et == 0) dp0 += sum4; else dp1 += sum4;
        u32 lo = f2bf(p0) | (f2bf(p1) << 16);
        u32 hi = f2bf(p2) | (f2bf(p3) << 16);
        *(uint2*)(PLb + (size_t)e * 272 + ((wh * 64 + lt * 16 + q * 4) << 1)) = make_uint2(lo, hi);
      }
    }
    __syncthreads();  // PL visible; Klds free
    if (it < 15) {    // stage K(it+1) overlapped with GEMM2
      const unsigned short* kb = Kg + (size_t)(it + 1) * 128 * 128;
#pragma unroll
      for (int j = 0; j < 4; j++) {
        int S = (j * 8 + w) * 64 + lane;
        int r = S >> 4, cp = S & 15, c = cp ^ (r & 15);
        gl_lds16(kb + (size_t)r * 128 + (c << 3), (char*)Klds + (j * 8 + w) * 1024);
      }
    }
    // GEMM2: O[d][e] += Vt_tile @ P^T
#pragma unroll
    for (int ks = 0; ks < 4; ks++) {
      s16x8 vf[4], pf[2];
#pragma unroll
      for (int dt = 0; dt < 4; dt++) {
        int d = wh * 64 + dt * 16 + l15;
        vf[dt] = *(const s16x8*)((char*)Vlds + d * 256 + (((ks * 4 + q) ^ l15) << 4));
      }
#pragma unroll
      for (int et = 0; et < 2; et++) {
        const int e = we * 32 + et * 16 + l15;
        pf[et] = *(const s16x8*)(PLb + (size_t)e * 272 + ks * 64 + q * 16);
      }
#pragma unroll
      for (int dt = 0; dt < 4; dt++)
#pragma unroll
        for (int et = 0; et < 2; et++)
          oacc[dt][et] = __builtin_amdgcn_mfma_f32_16x16x32_bf16(vf[dt], pf[et], oacc[dt][et], 0, 0, 0);
    }
    __syncthreads();  // Vlds/PL free
    if (it < 15) {    // stage Vt(it+1); L2 hits due to XCD swizzle
      const unsigned short* vb = Vtg + (size_t)(it + 1) * 128;
#pragma unroll
      for (int j = 0; j < 4; j++) {
        int S = (j * 8 + w) * 64 + lane;
        int r = S >> 4, cp = S & 15, c = cp ^ (r & 15);
        gl_lds16(vb + (size_t)r * 2048 + (c << 3), (char*)Vlds + (j * 8 + w) * 1024);
      }
      bitA = bitB;
    }
  }

  // denominator reduce (8 lanes contribute per e)
  atomicAdd(&sden[we * 32 + l15], dp0);
  atomicAdd(&sden[we * 32 + 16 + l15], dp1);
  __syncthreads();
  const float inv0 = 1.0f / sden[we * 32 + l15];
  const float inv1 = 1.0f / sden[we * 32 + 16 + l15];
  // O2[e][d] fp32, stride 132 (overlays dead K/V/PL buffers)
  float* O2 = (float*)smem;
#pragma unroll
  for (int dt = 0; dt < 4; dt++)
#pragma unroll
    for (int et = 0; et < 2; et++) {
      const int e = we * 32 + et * 16 + l15;
      const int d0 = wh * 64 + dt * 16 + q * 4;
      f32x4 v = oacc[dt][et];
      const float inv = et ? inv1 : inv0;
      float4 o;
      o.x = v[0] * inv; o.y = v[1] * inv; o.z = v[2] * inv; o.w = v[3] * inv;
      *(float4*)(O2 + e * 132 + d0) = o;
    }
  __syncthreads();
  // LayerNorm: 4 threads per token, 32 features each
  {
    const int e = tid >> 2, j = tid & 3;
    const float* row = O2 + e * 132 + j * 32;
    const float* gr = gateg + (size_t)e * 128 + j * 32;
    float4 x[8];
    float s1 = 0.f, s2 = 0.f;
#pragma unroll
    for (int i = 0; i < 8; i++) {
      float4 v = *(const float4*)(row + i * 4);
      float4 g = *(const float4*)(gr + i * 4);
      float4 hp;
      hp.x = v.x * g.x; hp.y = v.y * g.y; hp.z = v.z * g.z; hp.w = v.w * g.w;
      x[i] = hp;
      s1 += (hp.x + hp.y) + (hp.z + hp.w);
      s2 += (hp.x * hp.x + hp.y * hp.y) + (hp.z * hp.z + hp.w * hp.w);
    }
    s1 += __shfl_xor(s1, 1); s2 += __shfl_xor(s2, 1);
    s1 += __shfl_xor(s1, 2); s2 += __shfl_xor(s2, 2);
    const float mu = s1 * 0.0078125f;
    const float var = s2 * 0.0078125f - mu * mu;
    const float rs = rsqrtf(var + 1e-5f);
    float* orow = out + ((size_t)b * 2048 + e0 + e) * 128 + j * 32;
    const float* gg = ln_g + j * 32;
    const float* bb = ln_b + j * 32;
#pragma unroll
    for (int i = 0; i < 8; i++) {
      float4 gv = *(const float4*)(gg + i * 4);
      float4 bv = *(const float4*)(bb + i * 4);
      float4 o;
      o.x = (x[i].x - mu) * rs * gv.x + bv.x;
      o.y = (x[i].y - mu) * rs * gv.y + bv.y;
      o.z = (x[i].z - mu) * rs * gv.z + bv.z;
      o.w = (x[i].w - mu) * rs * gv.w + bv.w;
      *(float4*)(orow + i * 4) = o;
    }
  }
}

extern "C" void kernel_launch(void* const* d_in, const int* in_sizes, int n_in,
                              void* d_out, int out_size, void* d_ws, size_t ws_size,
                              hipStream_t stream) {
  const float* h = (const float*)d_in[0];
  const float* adj = (const float*)d_in[1];
  const float* op_emb = (const float*)d_in[2];
  const float* Wk = (const float*)d_in[3];
  const float* Wq = (const float*)d_in[4];
  const float* Wv = (const float*)d_in[5];
  const float* a_w = (const float*)d_in[6];
  const float* op_W = (const float*)d_in[7];
  const float* op_b = (const float*)d_in[8];
  const float* ln_g = (const float*)d_in[9];
  const float* ln_b = (const float*)d_in[10];
  char* ws = (char*)d_ws;
  float* out = (float*)d_out;

  k_adjbits<<<4096, 512, 0, stream>>>(adj, ws);          // adj -> 1-bit masks, streaming
  k0_wt<<<dim3(4, 16), 256, 0, stream>>>(Wq, Wk, Wv, a_w, op_W, ws);
  k1_proj<<<dim3(4, 256), 256, 0, stream>>>(h, op_emb, op_b, ws);
  k2_attn<<<256, 512, 0, stream>>>(ln_g, ln_b, ws, out);
}

// Round 4
// 468.342 us; speedup vs baseline: 1.0474x; 1.0313x over previous
//
#include <hip/hip_runtime.h>

typedef unsigned int u32;
typedef float f32x4 __attribute__((ext_vector_type(4)));
typedef short s16x8 __attribute__((ext_vector_type(8)));

#define LDA 136  // padded LDS row stride (bf16 elems) for k1

// workspace layout (bytes)
#define WQT_OFF 0ULL
#define WKT_OFF 32768ULL
#define WVT_OFF 65536ULL
#define OPWT_OFF 98304ULL
#define Q_OFF 114688ULL
#define K_OFF (Q_OFF + 8388608ULL)
#define VT_OFF (K_OFF + 8388608ULL)
#define GATE_OFF (VT_OFF + 8388608ULL)
// total ws need = GATE_OFF + 16 MiB ~= 40 MiB

__device__ __forceinline__ u32 f2bf(float f) {  // RNE float->bf16 bits
  u32 u = __float_as_uint(f);
  return (u + 0x7fffu + ((u >> 16) & 1u)) >> 16;
}

__device__ __forceinline__ void gl_lds16(const void* g, void* l) {
  __builtin_amdgcn_global_load_lds((const __attribute__((address_space(1))) void*)g,
                                   (__attribute__((address_space(3))) void*)l, 16, 0, 0);
}

// ---- k0: transpose weights to bf16; fold a_w * (1/sqrt(128)) * log2(e) into Wk^T ----
__global__ void k0_wt(const float* Wq, const float* Wk, const float* Wv,
                      const float* aw, const float* opW, char* ws) {
  int nt = blockIdx.x, part = blockIdx.y;
  int kksh = (nt == 3) ? 6 : 7;
  int KK = 1 << kksh;
  const float* S = (nt == 0) ? Wq : (nt == 1) ? Wk : (nt == 2) ? Wv : opW;
  unsigned short* D = (unsigned short*)(ws + (nt == 0 ? WQT_OFF : nt == 1 ? WKT_OFF : nt == 2 ? WVT_OFF : OPWT_OFF));
  int base = part * 8 * KK;
  for (int i = threadIdx.x; i < 8 * KK; i += 256) {
    int d = part * 8 + (i >> kksh), k = i & (KK - 1);
    float v = S[k * 128 + d];
    if (nt == 1) v *= aw[d] * 0.12751743f;  // (1/sqrt(128)) * log2(e)
    D[base + i] = (unsigned short)f2bf(v);
  }
}

// ---- k1: Q = h@Wq (bf16 [e][d]), K = h@Wk_scaled ([e][d]), Vt = (h@Wv)^T ([d][e]),
// ----     gate = sigmoid(op_emb@opW + op_b) (fp32 [e][d]) ----
__launch_bounds__(256, 2)
__global__ void k1_proj(const float* __restrict__ h, const float* __restrict__ op_emb,
                        const float* __restrict__ op_b, char* __restrict__ ws) {
  int nt = blockIdx.x, et = blockIdx.y;
  int kksh = (nt == 3) ? 6 : 7;
  int KK = 1 << kksh;
  __shared__ unsigned short bufA[128 * LDA];
  __shared__ unsigned short bufB[128 * LDA];
  unsigned short* wbuf = (nt == 2) ? bufB : bufA;
  unsigned short* xbuf = (nt == 2) ? bufA : bufB;
  const unsigned short* Wt = (const unsigned short*)(ws + (nt == 0 ? WQT_OFF : nt == 1 ? WKT_OFF : nt == 2 ? WVT_OFF : OPWT_OFF));
  {
    const uint4* Ws = (const uint4*)Wt;
    int cnt = 128 * KK / 8;
    for (int i = threadIdx.x; i < cnt; i += 256) {
      uint4 v = Ws[i];
      int r = (8 * i) >> kksh, c = (8 * i) & (KK - 1);
      *(uint4*)&wbuf[r * LDA + c] = v;
    }
  }
  {
    const float* X = (nt == 3) ? (op_emb + (size_t)et * 128 * 64) : (h + (size_t)et * 128 * 128);
    int cnt = 128 * KK / 4;
    for (int i = threadIdx.x; i < cnt; i += 256) {
      float4 v = *(const float4*)(X + 4 * i);
      int r = (4 * i) >> kksh, c = (4 * i) & (KK - 1);
      u32 lo = f2bf(v.x) | (f2bf(v.y) << 16);
      u32 hi = f2bf(v.z) | (f2bf(v.w) << 16);
      *(uint2*)&xbuf[r * LDA + c] = make_uint2(lo, hi);
    }
  }
  __syncthreads();
  int tid = threadIdx.x, w = tid >> 6, lane = tid & 63, l15 = lane & 15, q = lane >> 4;
  int wa = w >> 1, wb = w & 1;
  f32x4 acc[4][4];
#pragma unroll
  for (int a = 0; a < 4; a++)
#pragma unroll
    for (int bq = 0; bq < 4; bq++) acc[a][bq] = f32x4{0.f, 0.f, 0.f, 0.f};
  for (int ks = 0; ks < KK / 32; ks++) {
    s16x8 af[4], bf_[4];
#pragma unroll
    for (int mt = 0; mt < 4; mt++)
      af[mt] = *(const s16x8*)&bufA[(wa * 64 + mt * 16 + l15) * LDA + ks * 32 + q * 8];
#pragma unroll
    for (int n2 = 0; n2 < 4; n2++)
      bf_[n2] = *(const s16x8*)&bufB[(wb * 64 + n2 * 16 + l15) * LDA + ks * 32 + q * 8];
#pragma unroll
    for (int mt = 0; mt < 4; mt++)
#pragma unroll
      for (int n2 = 0; n2 < 4; n2++)
        acc[mt][n2] = __builtin_amdgcn_mfma_f32_16x16x32_bf16(af[mt], bf_[n2], acc[mt][n2], 0, 0, 0);
  }
  if (nt <= 1) {
    unsigned short* Dst = (unsigned short*)(ws + (nt == 0 ? Q_OFF : K_OFF));
#pragma unroll
    for (int mt = 0; mt < 4; mt++)
#pragma unroll
      for (int n2 = 0; n2 < 4; n2++) {
        int d0 = wa * 64 + mt * 16 + q * 4;
        int eg = et * 128 + wb * 64 + n2 * 16 + l15;
        f32x4 a = acc[mt][n2];
        u32 lo = f2bf(a[0]) | (f2bf(a[1]) << 16);
        u32 hi = f2bf(a[2]) | (f2bf(a[3]) << 16);
        *(uint2*)(Dst + (size_t)eg * 128 + d0) = make_uint2(lo, hi);
      }
  } else if (nt == 2) {
    unsigned short* Dst = (unsigned short*)(ws + VT_OFF);
    int b = et >> 4;
    int ein0 = (et & 15) * 128;
#pragma unroll
    for (int mt = 0; mt < 4; mt++)
#pragma unroll
      for (int n2 = 0; n2 < 4; n2++) {
        int e0b = ein0 + wa * 64 + mt * 16 + q * 4;
        int d = wb * 64 + n2 * 16 + l15;
        f32x4 a = acc[mt][n2];
        u32 lo = f2bf(a[0]) | (f2bf(a[1]) << 16);
        u32 hi = f2bf(a[2]) | (f2bf(a[3]) << 16);
        *(uint2*)(Dst + (size_t)b * 128 * 2048 + (size_t)d * 2048 + e0b) = make_uint2(lo, hi);
      }
  } else {
    float* Dst = (float*)(ws + GATE_OFF);
#pragma unroll
    for (int mt = 0; mt < 4; mt++)
#pragma unroll
      for (int n2 = 0; n2 < 4; n2++) {
        int d0 = wa * 64 + mt * 16 + q * 4;
        int eg = et * 128 + wb * 64 + n2 * 16 + l15;
        f32x4 a = acc[mt][n2];
        float4 g4;
        g4.x = 1.f / (1.f + __builtin_amdgcn_exp2f(-(a[0] + op_b[d0 + 0]) * 1.4426950f));
        g4.y = 1.f / (1.f + __builtin_amdgcn_exp2f(-(a[1] + op_b[d0 + 1]) * 1.4426950f));
        g4.z = 1.f / (1.f + __builtin_amdgcn_exp2f(-(a[2] + op_b[d0 + 2]) * 1.4426950f));
        g4.w = 1.f / (1.f + __builtin_amdgcn_exp2f(-(a[3] + op_b[d0 + 3]) * 1.4426950f));
        *(float4*)(Dst + (size_t)eg * 128 + d0) = g4;
      }
  }
}

// ---- k2: fused attention + gate + LayerNorm, single-barrier pipelined.
// LDS: Kbuf[2] 64K | Vbuf[2] 64K | PL (8 waves x 2304 B) | sden 512 B = 150016 B.
// Wave (wh, we): GEMM1 St[l in wh-half][e in we-quarter]; GEMM2 k-local:
// O_partial[e in we-quarter][all d] over its own l-half; partials merged in epilogue.
__launch_bounds__(512, 2)
__global__ void k2_attn(const float* __restrict__ adj, const float* __restrict__ ln_g,
                        const float* __restrict__ ln_b, char* __restrict__ ws,
                        float* __restrict__ out) {
  __shared__ char smem[150016];
  float* sden = (float*)(smem + 149504);

  const int bid = blockIdx.x;
  const int xcd = bid & 7, slot = bid >> 3;
  const int b = xcd * 2 + (slot >> 4);  // 2 batches per XCD for K/Vt L2 locality
  const int e0 = (slot & 15) << 7;

  const unsigned short* Qg = (const unsigned short*)(ws + Q_OFF) + ((size_t)b * 2048 + e0) * 128;
  const unsigned short* Kg = (const unsigned short*)(ws + K_OFF) + (size_t)b * 2048 * 128;
  const unsigned short* Vtg = (const unsigned short*)(ws + VT_OFF) + (size_t)b * 128 * 2048;
  const float* gateg = (const float*)(ws + GATE_OFF) + ((size_t)b * 2048 + e0) * 128;
  const float* adjg = adj + (size_t)b * 2048 * 2048 + (size_t)e0 * 2048;

  const int tid = threadIdx.x;
  const int w = tid >> 6, lane = tid & 63, l15 = lane & 15, q = lane >> 4;
  const int wh = w >> 2, we = w & 3;
  char* PLw = smem + 131072 + w * 2304;  // wave-private transform scratch (16 rows x 144 B)

  if (tid < 128) sden[tid] = 0.0f;

  // persistent Q B-frags: B[k=proj-dim][n=e]
  s16x8 qf[2][4];
#pragma unroll
  for (int et = 0; et < 2; et++) {
    const int e = we * 32 + et * 16 + l15;
#pragma unroll
    for (int ks = 0; ks < 4; ks++)
      qf[et][ks] = *(const s16x8*)(Qg + (size_t)e * 128 + ks * 32 + q * 8);
  }

  // O partial accumulators: C2[m=e (2 et-tiles)][n=d (8 nt-tiles)], over this wave's l-half
  f32x4 oacc[2][8];
#pragma unroll
  for (int et = 0; et < 2; et++)
#pragma unroll
    for (int nt = 0; nt < 8; nt++) oacc[et][nt] = f32x4{0.f, 0.f, 0.f, 0.f};
  float dp0 = 0.0f, dp1 = 0.0f;
  float4 adjB[2][4];

  // prolog: stage tile 0 into buffer 0 (XOR chunk swizzle c^(r&15)); load adj(0)
#pragma unroll
  for (int j = 0; j < 4; j++) {
    int S = (j * 8 + w) * 64 + lane;
    int r = S >> 4, cp = S & 15, c = cp ^ (r & 15);
    gl_lds16(Kg + (size_t)r * 128 + (c << 3), smem + (j * 8 + w) * 1024);
    gl_lds16(Vtg + (size_t)r * 2048 + (c << 3), smem + 65536 + (j * 8 + w) * 1024);
  }
#pragma unroll
  for (int et = 0; et < 2; et++) {
    const int e = we * 32 + et * 16 + l15;
#pragma unroll
    for (int lt = 0; lt < 4; lt++)
      adjB[et][lt] = *(const float4*)(adjg + (size_t)e * 2048 + wh * 64 + lt * 16 + q * 4);
  }

#pragma unroll 2
  for (int it = 0; it < 16; it++) {
    __syncthreads();  // stages(it) drained (vmcnt(0) at barrier), adj(it) in adjB
    const int cur = it & 1, nxt = cur ^ 1;
    char* Kl = smem + cur * 32768;
    char* Vl = smem + 65536 + cur * 32768;
    float4 adjA[2][4];
#pragma unroll
    for (int et = 0; et < 2; et++)
#pragma unroll
      for (int lt = 0; lt < 4; lt++) adjA[et][lt] = adjB[et][lt];

    if (it < 15) {  // issue next-tile DMA + adj prefetch immediately (full iter in flight)
      const unsigned short* kb = Kg + (size_t)(it + 1) * 16384;
      const unsigned short* vb = Vtg + (size_t)(it + 1) * 128;
      char* Kd = smem + nxt * 32768;
      char* Vd = smem + 65536 + nxt * 32768;
#pragma unroll
      for (int j = 0; j < 4; j++) {
        int S = (j * 8 + w) * 64 + lane;
        int r = S >> 4, cp = S & 15, c = cp ^ (r & 15);
        gl_lds16(kb + (size_t)r * 128 + (c << 3), Kd + (j * 8 + w) * 1024);
        gl_lds16(vb + (size_t)r * 2048 + (c << 3), Vd + (j * 8 + w) * 1024);
      }
      const float* ab = adjg + (size_t)(it + 1) * 128;
#pragma unroll
      for (int et = 0; et < 2; et++) {
        const int e = we * 32 + et * 16 + l15;
#pragma unroll
        for (int lt = 0; lt < 4; lt++)
          adjB[et][lt] = *(const float4*)(ab + (size_t)e * 2048 + wh * 64 + lt * 16 + q * 4);
      }
    }

    // GEMM1: St[l][e], A = K-frags (m=l), B = qf (n=e); scale pre-folded into K
    f32x4 sacc[4][2];
#pragma unroll
    for (int lt = 0; lt < 4; lt++)
#pragma unroll
      for (int et = 0; et < 2; et++) sacc[lt][et] = f32x4{0.f, 0.f, 0.f, 0.f};
#pragma unroll
    for (int ks = 0; ks < 4; ks++) {
      s16x8 kf[4];
#pragma unroll
      for (int lt = 0; lt < 4; lt++) {
        int l = wh * 64 + lt * 16 + l15;
        kf[lt] = *(const s16x8*)(Kl + l * 256 + (((ks * 4 + q) ^ l15) << 4));
      }
#pragma unroll
      for (int lt = 0; lt < 4; lt++)
#pragma unroll
        for (int et = 0; et < 2; et++)
          sacc[lt][et] = __builtin_amdgcn_mfma_f32_16x16x32_bf16(kf[lt], qf[et][ks], sacc[lt][et], 0, 0, 0);
    }

    // elementwise P = exp2(lrelu(s)*adj)  (adj in {0,1}: adj=0 -> exp2(0)=1),
    // then C-layout -> A-layout via wave-private LDS (no barrier, lgkm only)
    s16x8 af[2][2];
#pragma unroll
    for (int et = 0; et < 2; et++) {
      u32 pqw[4][2];
      float dsum = 0.0f;
#pragma unroll
      for (int lt = 0; lt < 4; lt++) {
        float4 aj = adjA[et][lt];
        f32x4 s = sacc[lt][et];
        float p0 = __builtin_amdgcn_exp2f(fmaxf(s[0], 0.2f * s[0]) * aj.x);
        float p1 = __builtin_amdgcn_exp2f(fmaxf(s[1], 0.2f * s[1]) * aj.y);
        float p2 = __builtin_amdgcn_exp2f(fmaxf(s[2], 0.2f * s[2]) * aj.z);
        float p3 = __builtin_amdgcn_exp2f(fmaxf(s[3], 0.2f * s[3]) * aj.w);
        dsum += (p0 + p1) + (p2 + p3);
        pqw[lt][0] = f2bf(p0) | (f2bf(p1) << 16);
        pqw[lt][1] = f2bf(p2) | (f2bf(p3) << 16);
      }
      if (et == 0) dp0 += dsum; else dp1 += dsum;
#pragma unroll
      for (int lt = 0; lt < 4; lt++)
        *(uint2*)(PLw + l15 * 144 + lt * 32 + q * 8) = make_uint2(pqw[lt][0], pqw[lt][1]);
      af[et][0] = *(const s16x8*)(PLw + l15 * 144 + q * 16);        // kk = q*8..q*8+7
      af[et][1] = *(const s16x8*)(PLw + l15 * 144 + 64 + q * 16);   // kk = 32+q*8..
    }

    // GEMM2 (k-local over this wave's l-half): O[e][d] += P[e][kk] * Vt[d][kk]
#pragma unroll
    for (int ks2 = 0; ks2 < 2; ks2++) {
      s16x8 vf[8];
#pragma unroll
      for (int nt = 0; nt < 8; nt++) {
        int d = nt * 16 + l15;
        vf[nt] = *(const s16x8*)(Vl + d * 256 + (((wh * 8 + ks2 * 4 + q) ^ l15) << 4));
      }
#pragma unroll
      for (int et = 0; et < 2; et++)
#pragma unroll
        for (int nt = 0; nt < 8; nt++)
          oacc[et][nt] = __builtin_amdgcn_mfma_f32_16x16x32_bf16(af[et][ks2], vf[nt], oacc[et][nt], 0, 0, 0);
    }
  }

  // denominators (8 contributors per e: 4 q-lanes x 2 wh-waves)
  atomicAdd(&sden[we * 32 + l15], dp0);
  atomicAdd(&sden[we * 32 + 16 + l15], dp1);
  __syncthreads();

  // merge wh partials in O2 [e][d] fp32 (stride 132), overlays dead K/V buffers
  float* O2 = (float*)smem;
  if (wh == 1) {
#pragma unroll
    for (int et = 0; et < 2; et++)
#pragma unroll
      for (int nt = 0; nt < 8; nt++) {
        const int eb = we * 32 + et * 16 + q * 4;
        const int d = nt * 16 + l15;
#pragma unroll
        for (int r = 0; r < 4; r++) O2[(eb + r) * 132 + d] = oacc[et][nt][r];
      }
  }
  __syncthreads();
  if (wh == 0) {
#pragma unroll
    for (int et = 0; et < 2; et++) {
      const int eb = we * 32 + et * 16 + q * 4;
      float inv[4];
#pragma unroll
      for (int r = 0; r < 4; r++) inv[r] = 1.0f / sden[eb + r];
#pragma unroll
      for (int nt = 0; nt < 8; nt++) {
        const int d = nt * 16 + l15;
#pragma unroll
        for (int r = 0; r < 4; r++) {
          int idx = (eb + r) * 132 + d;
          O2[idx] = (O2[idx] + oacc[et][nt][r]) * inv[r];
        }
      }
    }
  }
  __syncthreads();

  // LayerNorm: 4 threads per token, 32 features each
  {
    const int e = tid >> 2, j = tid & 3;
    const float* row = O2 + e * 132 + j * 32;
    const float* gr = gateg + (size_t)e * 128 + j * 32;
    float4 x[8];
    float s1 = 0.f, s2 = 0.f;
#pragma unroll
    for (int i = 0; i < 8; i++) {
      float4 v = *(const float4*)(row + i * 4);
      float4 g = *(const float4*)(gr + i * 4);
      float4 hp;
      hp.x = v.x * g.x; hp.y = v.y * g.y; hp.z = v.z * g.z; hp.w = v.w * g.w;
      x[i] = hp;
      s1 += (hp.x + hp.y) + (hp.z + hp.w);
      s2 += (hp.x * hp.x + hp.y * hp.y) + (hp.z * hp.z + hp.w * hp.w);
    }
    s1 += __shfl_xor(s1, 1); s2 += __shfl_xor(s2, 1);
    s1 += __shfl_xor(s1, 2); s2 += __shfl_xor(s2, 2);
    const float mu = s1 * 0.0078125f;
    const float var = s2 * 0.0078125f - mu * mu;
    const float rs = rsqrtf(var + 1e-5f);
    float* orow = out + ((size_t)b * 2048 + e0 + e) * 128 + j * 32;
    const float* gg = ln_g + j * 32;
    const float* bb = ln_b + j * 32;
#pragma unroll
    for (int i = 0; i < 8; i++) {
      float4 gv = *(const float4*)(gg + i * 4);
      float4 bv = *(const float4*)(bb + i * 4);
      float4 o;
      o.x = (x[i].x - mu) * rs * gv.x + bv.x;
      o.y = (x[i].y - mu) * rs * gv.y + bv.y;
      o.z = (x[i].z - mu) * rs * gv.z + bv.z;
      o.w = (x[i].w - mu) * rs * gv.w + bv.w;
      *(float4*)(orow + i * 4) = o;
    }
  }
}

extern "C" void kernel_launch(void* const* d_in, const int* in_sizes, int n_in,
                              void* d_out, int out_size, void* d_ws, size_t ws_size,
                              hipStream_t stream) {
  const float* h = (const float*)d_in[0];
  const float* adj = (const float*)d_in[1];
  const float* op_emb = (const float*)d_in[2];
  const float* Wk = (const float*)d_in[3];
  const float* Wq = (const float*)d_in[4];
  const float* Wv = (const float*)d_in[5];
  const float* a_w = (const float*)d_in[6];
  const float* op_W = (const float*)d_in[7];
  const float* op_b = (const float*)d_in[8];
  const float* ln_g = (const float*)d_in[9];
  const float* ln_b = (const float*)d_in[10];
  char* ws = (char*)d_ws;
  float* out = (float*)d_out;

  k0_wt<<<dim3(4, 16), 256, 0, stream>>>(Wq, Wk, Wv, a_w, op_W, ws);
  k1_proj<<<dim3(4, 256), 256, 0, stream>>>(h, op_emb, op_b, ws);
  k2_attn<<<256, 512, 0, stream>>>(adj, ln_g, ln_b, ws, out);
}